// Round 3
// baseline (136.221 us; speedup 1.0000x reference)
//
#include <hip/hip_runtime.h>
#include <stdint.h>

// Problem constants (fixed shapes from reference)
#define M_ROWS 6272   // 32*196
#define K_DIM  768
#define N_DIM  3072
#define BM 128
#define BN 256
#define BK 32
#define NITER (K_DIM / BK)   // 24

#define X_CHUNKS (M_ROWS * K_DIM / 8)   // 602112
#define W_CHUNKS (N_DIM * K_DIM / 8)    // 294912
#define X_BLOCKS (X_CHUNKS / 256)       // 2352
#define W_BLOCKS (W_CHUNKS / 256)       // 1152

#define GRID_X (N_DIM / BN)             // 12
#define GRID_Y (M_ROWS / BM)            // 49
#define NWG    (GRID_X * GRID_Y)        // 588

typedef unsigned short u16;
typedef __attribute__((ext_vector_type(8))) __bf16 bf16x8;
typedef __attribute__((ext_vector_type(4))) float f32x4;

__device__ __forceinline__ u16 f32_to_bf16(float f) {
    unsigned u = __float_as_uint(f);
    unsigned r = 0x7FFFu + ((u >> 16) & 1u);
    return (u16)((u + r) >> 16);
}

__device__ __forceinline__ unsigned pack2(float a, float b) {
    return (unsigned)f32_to_bf16(a) | ((unsigned)f32_to_bf16(b) << 16);
}

// LDS-only barrier: drains lgkmcnt (ds ops) but deliberately NOT vmcnt, so
// in-flight global_load_lds DMA rides across the barrier (counted vmcnt
// handles it separately -- never drain to 0 in the main loop).
__device__ __forceinline__ void lds_barrier() {
    asm volatile("s_waitcnt lgkmcnt(0)\n\ts_barrier" ::: "memory");
}

// Async global->LDS DMA, 16B per lane. LDS dest is wave-uniform base +
// lane*16 (hardware rule); global source is per-lane.
#define GLOAD16(gp, lp) __builtin_amdgcn_global_load_lds( \
    (const __attribute__((address_space(1))) void*)(gp),  \
    (__attribute__((address_space(3))) void*)(lp), 16, 0, 0)

// Fused prep (verified): blocks [0, X_BLOCKS) cast x fp32->bf16;
// blocks [X_BLOCKS, X_BLOCKS+W_BLOCKS) expand block-circulant W to bf16.
__global__ void prep_kernel(const float* __restrict__ x, const float* __restrict__ w,
                            u16* __restrict__ xb, u16* __restrict__ wb) {
    int b = blockIdx.x;
    if (b < X_BLOCKS) {
        int idx = b * 256 + threadIdx.x;
        const float4* xp = (const float4*)x + (size_t)idx * 2;
        float4 a = xp[0], c = xp[1];
        uint4 v;
        v.x = pack2(a.x, a.y);
        v.y = pack2(a.z, a.w);
        v.z = pack2(c.x, c.y);
        v.w = pack2(c.z, c.w);
        ((uint4*)xb)[idx] = v;
    } else {
        int idx = (b - X_BLOCKS) * 256 + threadIdx.x;
        int n    = idx / 96;          // output row [0,3072)
        int kc   = idx - n * 96;      // 8-elem chunk along K
        int kblk = n / 768;           // 0..3
        int o    = n - kblk * 768;    // 0..767
        int j    = kc / 24;           // 0..3
        int c8   = kc - j * 24;       // 0..23
        int i    = (kblk - j) & 3;    // (kblk - j) mod 4
        const float* src = w + (((size_t)i * 768 + o) * 192 + c8 * 8);
        float4 a = ((const float4*)src)[0];
        float4 c = ((const float4*)src)[1];
        uint4 v;
        v.x = pack2(a.x, a.y);
        v.y = pack2(a.z, a.w);
        v.z = pack2(c.x, c.y);
        v.w = pack2(c.z, c.w);
        ((uint4*)wb)[idx] = v;
    }
}

// C[m,n] = sum_k A[m,k]*B[n,k] + bias[n]; A,B bf16 row-major K-contig, C fp32.
//
// Triple-buffered global_load_lds pipeline (this round's change):
//   - 3 LDS buffers of one K-tile each (A 8KB + B 16KB): while computing kt
//     from buf kt%3, tile kt+1 sits landed in buf (kt+1)%3, and tile kt+2's
//     3 DMA issues/thread target buf (kt+2)%3 (freed at kt-1's barrier).
//   - steady-state wait is s_waitcnt vmcnt(3) (kt+1's 3 loads retire, kt+2's
//     3 stay in flight), placed BEFORE the barrier so landing is collective.
//     vmcnt never drains to 0 until the epilogue (T4).
//   - removes the per-iteration reg round-trip (3 global_load + 3 ds_write
//     per thread) of the previous version entirely.
//
// Data layout is bit-identical to the verified reg-staged kernel: DMA lane
// mapping (wave-uniform base + lane*16) lands chunk tid exactly where
// Al0[0]=ga0 used to; same XOR swizzle (slot ^ ((row>>1)&3)) applied on the
// per-lane GLOBAL source, mirrored on the ds_read side (conflicts=0).
//
// XCD-chunked bijective block swizzle (m204) unchanged.
__global__ __launch_bounds__(512, 4) void gemm_bt(
    const u16* __restrict__ A,    // [M_ROWS, K_DIM] bf16
    const u16* __restrict__ B,    // [N_DIM,  K_DIM] bf16
    const float* __restrict__ bias,
    float* __restrict__ C)
{
    __shared__ __align__(16) u16 As[3][BM * BK];   // 3 x 8 KB
    __shared__ __align__(16) u16 Bs[3][BN * BK];   // 3 x 16 KB  (72 KB total)

    // ---- XCD-aware bijective remap of the 1-D block id ----
    const int orig = blockIdx.x;
    const int xcd  = orig & 7;
    const int pos  = orig >> 3;
    const int q    = NWG >> 3;          // 73
    const int r    = NWG & 7;           // 4
    const int lin  = (xcd < r ? xcd * (q + 1) : r * (q + 1) + (xcd - r) * q) + pos;
    const int rowBlk = lin / GRID_X;    // 0..48
    const int colBlk = lin - rowBlk * GRID_X;

    const int rowBase = rowBlk * BM;
    const int colBase = colBlk * BN;

    const int tid    = threadIdx.x;
    const int wave   = tid >> 6;
    const int lane   = tid & 63;
    const int lane16 = lane & 15;
    const int quad   = lane >> 4;
    const int wr     = wave >> 2;   // wave row (0..1) -> 64 rows each
    const int wc     = wave & 3;    // wave col (0..3) -> 64 cols each

    // DMA source addressing (identical index math to the verified staging):
    // chunk c: row = c>>2, lds slot = c&3, global k-slot = (c&3)^((row>>1)&3).
    const int cA  = tid;
    const int rA  = cA >> 2,  sA  = (cA & 3) ^ ((rA >> 1) & 3);
    const int cB0 = tid;
    const int cB1 = tid + 512;
    const int rB0 = cB0 >> 2, sB0 = (cB0 & 3) ^ ((rB0 >> 1) & 3);
    const int rB1 = cB1 >> 2, sB1 = (cB1 & 3) ^ ((rB1 >> 1) & 3);

    const uint4* Ag  = (const uint4*)(A + (size_t)(rowBase + rA) * K_DIM + sA * 8);
    const uint4* Bg0 = (const uint4*)(B + (size_t)(colBase + rB0) * K_DIM + sB0 * 8);
    const uint4* Bg1 = (const uint4*)(B + (size_t)(colBase + rB1) * K_DIM + sB1 * 8);

    // DMA dest: wave-uniform base; HW adds lane*16 -> chunk tid lands at
    // element tid*8, exactly the old Al0/Bl0/Bl1 placement.
    char* AsB = (char*)As + wave * 1024;
    char* BsB = (char*)Bs + wave * 1024;

#define ISSUE(g, b) do {                                     \
        GLOAD16(Ag  + (g) * 4, AsB + (b) * 8192);            \
        GLOAD16(Bg0 + (g) * 4, BsB + (b) * 16384);           \
        GLOAD16(Bg1 + (g) * 4, BsB + (b) * 16384 + 8192);    \
    } while (0)

    // read-side swizzle (unchanged, verified conflicts=0)
    const int swz  = (lane16 >> 1) & 3;
    const int slot = (quad ^ swz) * 8;
    int aoff[4], boff[4];
#pragma unroll
    for (int i = 0; i < 4; ++i)
        aoff[i] = (wr * 64 + i * 16 + lane16) * BK + slot;
#pragma unroll
    for (int j = 0; j < 4; ++j)
        boff[j] = (wc * 64 + j * 16 + lane16) * BK + slot;

    f32x4 acc[4][4] = {};

#define DS_READS(cb)                                                        \
    _Pragma("unroll") for (int i = 0; i < 4; ++i)                           \
        af[i] = *(const bf16x8*)&As[cb][aoff[i]];                           \
    _Pragma("unroll") for (int j = 0; j < 4; ++j)                           \
        bfv[j] = *(const bf16x8*)&Bs[cb][boff[j]];

#define MFMA16()                                                            \
    __builtin_amdgcn_s_setprio(1);                                          \
    _Pragma("unroll") for (int i = 0; i < 4; ++i)                           \
    _Pragma("unroll") for (int j = 0; j < 4; ++j)                           \
        acc[i][j] = __builtin_amdgcn_mfma_f32_16x16x32_bf16(                \
            af[i], bfv[j], acc[i][j], 0, 0, 0);                             \
    __builtin_amdgcn_s_setprio(0);

    // steady state: reads of kt (safe: kt landed collectively at kt-1's
    // vmcnt+barrier), issue kt+2 (safe: its buffer's last reads drained at
    // kt-1's barrier), land kt+1 (vmcnt 3, kt+2 stays in flight), barrier,
    // MFMA (overlaps with next iteration's ds_reads after the barrier).
#define ITER_ISSUE(cb, fb, g) {                                             \
        bf16x8 af[4], bfv[4];                                               \
        DS_READS(cb)                                                        \
        ISSUE(g, fb);                                                       \
        asm volatile("s_waitcnt vmcnt(3)" ::: "memory");                    \
        lds_barrier();                                                      \
        MFMA16()                                                            \
    }

#define ITER_DRAIN(cb) {                                                    \
        bf16x8 af[4], bfv[4];                                               \
        DS_READS(cb)                                                        \
        asm volatile("s_waitcnt vmcnt(0)" ::: "memory");                    \
        lds_barrier();                                                      \
        MFMA16()                                                            \
    }

#define ITER_FINAL(cb) {                                                    \
        bf16x8 af[4], bfv[4];                                               \
        DS_READS(cb)                                                        \
        MFMA16()                                                            \
    }

    // prologue: tiles 0 and 1 in flight; land tile 0 (tile 1 stays in flight)
    ISSUE(0, 0);
    ISSUE(1, 1);
    asm volatile("s_waitcnt vmcnt(3)\n\ts_barrier" ::: "memory");

    // kt = 0..20 (buffer pattern repeats mod 3), each issues kt+2
    for (int t = 0; t < 7; ++t) {
        const int g = t * 3;
        ITER_ISSUE(0, 2, g + 2);
        ITER_ISSUE(1, 0, g + 3);
        ITER_ISSUE(2, 1, g + 4);
    }
    ITER_ISSUE(0, 2, 23);   // kt=21: issues last tile (23)
    ITER_DRAIN(1);          // kt=22: land tile 23 (vmcnt 0, epilogue-adjacent)
    ITER_FINAL(2);          // kt=23: compute only

    // epilogue: C[row][col] = acc + bias[col]  (verified layout)
    float bv[4];
#pragma unroll
    for (int j = 0; j < 4; ++j)
        bv[j] = bias[colBase + wc * 64 + j * 16 + lane16];
#pragma unroll
    for (int i = 0; i < 4; ++i) {
        int row0 = rowBase + wr * 64 + i * 16 + quad * 4;
#pragma unroll
        for (int r2 = 0; r2 < 4; ++r2) {
            float* cp = C + (size_t)(row0 + r2) * N_DIM + colBase + wc * 64 + lane16;
#pragma unroll
            for (int j = 0; j < 4; ++j)
                cp[j * 16] = acc[i][j][r2] + bv[j];
        }
    }
#undef ISSUE
#undef DS_READS
#undef MFMA16
#undef ITER_ISSUE
#undef ITER_DRAIN
#undef ITER_FINAL
}

extern "C" void kernel_launch(void* const* d_in, const int* in_sizes, int n_in,
                              void* d_out, int out_size, void* d_ws, size_t ws_size,
                              hipStream_t stream) {
    const float* x    = (const float*)d_in[0];
    const float* w    = (const float*)d_in[1];
    const float* bias = (const float*)d_in[2];
    float* out = (float*)d_out;

    u16* xb = (u16*)d_ws;                                       // 9,633,792 B
    u16* wb = (u16*)((char*)d_ws + (size_t)M_ROWS * K_DIM * 2); // +4,718,592 B

    hipLaunchKernelGGL(prep_kernel, dim3(X_BLOCKS + W_BLOCKS), dim3(256),
                       0, stream, x, w, xb, wb);
    hipLaunchKernelGGL(gemm_bt, dim3(NWG), dim3(512),
                       0, stream, xb, wb, bias, out);
}

// Round 4
// 135.903 us; speedup vs baseline: 1.0023x; 1.0023x over previous
//
#include <hip/hip_runtime.h>
#include <stdint.h>

// Problem constants (fixed shapes from reference)
#define M_ROWS 6272   // 32*196
#define K_DIM  768
#define N_DIM  3072
#define BM 128
#define BN 256
#define BK 32
#define NITER (K_DIM / BK)   // 24

#define X_CHUNKS (M_ROWS * K_DIM / 8)   // 602112
#define W_CHUNKS (N_DIM * K_DIM / 8)    // 294912
#define X_BLOCKS (X_CHUNKS / 256)       // 2352
#define W_BLOCKS (W_CHUNKS / 256)       // 1152

#define GRID_X (N_DIM / BN)             // 12
#define GRID_Y (M_ROWS / BM)            // 49
#define NWG    (GRID_X * GRID_Y)        // 588

typedef unsigned short u16;
typedef __attribute__((ext_vector_type(8))) __bf16 bf16x8;
typedef __attribute__((ext_vector_type(4))) float f32x4;

__device__ __forceinline__ u16 f32_to_bf16(float f) {
    unsigned u = __float_as_uint(f);
    unsigned r = 0x7FFFu + ((u >> 16) & 1u);
    return (u16)((u + r) >> 16);
}

__device__ __forceinline__ unsigned pack2(float a, float b) {
    return (unsigned)f32_to_bf16(a) | ((unsigned)f32_to_bf16(b) << 16);
}

// Async global->LDS DMA, 16B per lane. LDS dest is wave-uniform base +
// lane*16 (hardware rule); global source is per-lane.
#define GLOAD16(gp, lp) __builtin_amdgcn_global_load_lds( \
    (const __attribute__((address_space(1))) void*)(gp),  \
    (__attribute__((address_space(3))) void*)(lp), 16, 0, 0)

// Fused prep (verified): blocks [0, X_BLOCKS) cast x fp32->bf16;
// blocks [X_BLOCKS, X_BLOCKS+W_BLOCKS) expand block-circulant W to bf16.
__global__ void prep_kernel(const float* __restrict__ x, const float* __restrict__ w,
                            u16* __restrict__ xb, u16* __restrict__ wb) {
    int b = blockIdx.x;
    if (b < X_BLOCKS) {
        int idx = b * 256 + threadIdx.x;
        const float4* xp = (const float4*)x + (size_t)idx * 2;
        float4 a = xp[0], c = xp[1];
        uint4 v;
        v.x = pack2(a.x, a.y);
        v.y = pack2(a.z, a.w);
        v.z = pack2(c.x, c.y);
        v.w = pack2(c.z, c.w);
        ((uint4*)xb)[idx] = v;
    } else {
        int idx = (b - X_BLOCKS) * 256 + threadIdx.x;
        int n    = idx / 96;          // output row [0,3072)
        int kc   = idx - n * 96;      // 8-elem chunk along K
        int kblk = n / 768;           // 0..3
        int o    = n - kblk * 768;    // 0..767
        int j    = kc / 24;           // 0..3
        int c8   = kc - j * 24;       // 0..23
        int i    = (kblk - j) & 3;    // (kblk - j) mod 4
        const float* src = w + (((size_t)i * 768 + o) * 192 + c8 * 8);
        float4 a = ((const float4*)src)[0];
        float4 c = ((const float4*)src)[1];
        uint4 v;
        v.x = pack2(a.x, a.y);
        v.y = pack2(a.z, a.w);
        v.z = pack2(c.x, c.y);
        v.w = pack2(c.z, c.w);
        ((uint4*)wb)[idx] = v;
    }
}

// C[m,n] = sum_k A[m,k]*B[n,k] + bias[n]; A,B bf16 row-major K-contig, C fp32.
//
// Round-4 change: 2-phase interleave per K-iteration (T3 mechanism) on the
// verified round-3 triple-buffered DMA skeleton. Per iter:
//   P0: ds_read af[0..3]+bf[0..1], issue A+B0 DMA for t+2, barrier,
//       setprio(1), 8 MFMA (j=0,1), setprio(0), barrier
//   P1: ds_read bf[2..3], issue B1 DMA, vmcnt(3) [retire tile t+1, keep
//       t+2 in flight], barrier, setprio(1), 8 MFMA (j=2,3), setprio(0),
//       barrier
// Reads ride in flight across the pre-MFMA barrier (waves cross with lgkm
// outstanding; compiler inserts per-wave lgkm waits before MFMA use). The
// phase barriers keep the 8 waves' MFMA clusters aligned so LDS and matrix
// pipes interleave; setprio now has a role-split to arbitrate (T5).
//
// Triple-buffer ledger (unchanged from verified round-3): reading buf t%3,
// tile t+1 landed in (t+1)%3, DMA for t+2 targets (t+2)%3 (its last reads
// drained two barriers ago). Steady outstanding = 6 loads; vmcnt(3) retires
// exactly tile t+1's 3. vmcnt never drains to 0 until the tail.
//
// DMA layout, XOR swizzle (conflicts=0 verified), epilogue: bit-identical
// to round-3. XCD-chunked bijective block swizzle (m204) unchanged.
__global__ __launch_bounds__(512, 4) void gemm_bt(
    const u16* __restrict__ A,    // [M_ROWS, K_DIM] bf16
    const u16* __restrict__ B,    // [N_DIM,  K_DIM] bf16
    const float* __restrict__ bias,
    float* __restrict__ C)
{
    __shared__ __align__(16) u16 As[3][BM * BK];   // 3 x 8 KB
    __shared__ __align__(16) u16 Bs[3][BN * BK];   // 3 x 16 KB  (72 KB total)

    // ---- XCD-aware bijective remap of the 1-D block id ----
    const int orig = blockIdx.x;
    const int xcd  = orig & 7;
    const int pos  = orig >> 3;
    const int q    = NWG >> 3;          // 73
    const int r    = NWG & 7;           // 4
    const int lin  = (xcd < r ? xcd * (q + 1) : r * (q + 1) + (xcd - r) * q) + pos;
    const int rowBlk = lin / GRID_X;    // 0..48
    const int colBlk = lin - rowBlk * GRID_X;

    const int rowBase = rowBlk * BM;
    const int colBase = colBlk * BN;

    const int tid    = threadIdx.x;
    const int wave   = tid >> 6;
    const int lane   = tid & 63;
    const int lane16 = lane & 15;
    const int quad   = lane >> 4;
    const int wr     = wave >> 2;   // wave row (0..1) -> 64 rows each
    const int wc     = wave & 3;    // wave col (0..3) -> 64 cols each

    // DMA source addressing (identical index math to the verified staging):
    // chunk c: row = c>>2, lds slot = c&3, global k-slot = (c&3)^((row>>1)&3).
    const int cA  = tid;
    const int rA  = cA >> 2,  sA  = (cA & 3) ^ ((rA >> 1) & 3);
    const int cB0 = tid;
    const int cB1 = tid + 512;
    const int rB0 = cB0 >> 2, sB0 = (cB0 & 3) ^ ((rB0 >> 1) & 3);
    const int rB1 = cB1 >> 2, sB1 = (cB1 & 3) ^ ((rB1 >> 1) & 3);

    const uint4* Ag  = (const uint4*)(A + (size_t)(rowBase + rA) * K_DIM + sA * 8);
    const uint4* Bg0 = (const uint4*)(B + (size_t)(colBase + rB0) * K_DIM + sB0 * 8);
    const uint4* Bg1 = (const uint4*)(B + (size_t)(colBase + rB1) * K_DIM + sB1 * 8);

    // DMA dest: wave-uniform base; HW adds lane*16 -> chunk tid lands at
    // element tid*8, exactly the verified placement.
    char* AsB = (char*)As + wave * 1024;
    char* BsB = (char*)Bs + wave * 1024;

    // read-side swizzle (unchanged, verified conflicts=0)
    const int swz  = (lane16 >> 1) & 3;
    const int slot = (quad ^ swz) * 8;
    int aoff[4], boff[4];
#pragma unroll
    for (int i = 0; i < 4; ++i)
        aoff[i] = (wr * 64 + i * 16 + lane16) * BK + slot;
#pragma unroll
    for (int j = 0; j < 4; ++j)
        boff[j] = (wc * 64 + j * 16 + lane16) * BK + slot;

    f32x4 acc[4][4] = {};

    // ---- 2-phase iteration bodies ----
#define MFMA_HALF(J0)                                                       \
    __builtin_amdgcn_s_setprio(1);                                          \
    _Pragma("unroll") for (int i = 0; i < 4; ++i)                           \
    _Pragma("unroll") for (int j = (J0); j < (J0) + 2; ++j)                 \
        acc[i][j] = __builtin_amdgcn_mfma_f32_16x16x32_bf16(                \
            af[i], bfv[j], acc[i][j], 0, 0, 0);                             \
    __builtin_amdgcn_s_setprio(0);

    // steady-state iter: read buf rt, issue tile g -> buf wt, vmcnt(3)
#define ITER_ISSUE(rt, wt, g) {                                             \
        bf16x8 af[4], bfv[4];                                               \
        _Pragma("unroll") for (int i = 0; i < 4; ++i)                       \
            af[i] = *(const bf16x8*)&As[rt][aoff[i]];                       \
        _Pragma("unroll") for (int j = 0; j < 2; ++j)                       \
            bfv[j] = *(const bf16x8*)&Bs[rt][boff[j]];                      \
        GLOAD16(Ag  + (g) * 4, AsB + (wt) * 8192);                          \
        GLOAD16(Bg0 + (g) * 4, BsB + (wt) * 16384);                         \
        asm volatile("s_barrier" ::: "memory");                             \
        MFMA_HALF(0)                                                        \
        asm volatile("s_barrier" ::: "memory");                             \
        _Pragma("unroll") for (int j = 2; j < 4; ++j)                       \
            bfv[j] = *(const bf16x8*)&Bs[rt][boff[j]];                      \
        GLOAD16(Bg1 + (g) * 4, BsB + (wt) * 16384 + 8192);                  \
        asm volatile("s_waitcnt vmcnt(3)" ::: "memory");                    \
        asm volatile("s_barrier" ::: "memory");                             \
        MFMA_HALF(2)                                                        \
        asm volatile("s_barrier" ::: "memory");                             \
    }

    // drain iter: no issue, land the final tile (vmcnt 0)
#define ITER_DRAIN(rt) {                                                    \
        bf16x8 af[4], bfv[4];                                               \
        _Pragma("unroll") for (int i = 0; i < 4; ++i)                       \
            af[i] = *(const bf16x8*)&As[rt][aoff[i]];                       \
        _Pragma("unroll") for (int j = 0; j < 2; ++j)                       \
            bfv[j] = *(const bf16x8*)&Bs[rt][boff[j]];                      \
        asm volatile("s_barrier" ::: "memory");                             \
        MFMA_HALF(0)                                                        \
        asm volatile("s_barrier" ::: "memory");                             \
        _Pragma("unroll") for (int j = 2; j < 4; ++j)                       \
            bfv[j] = *(const bf16x8*)&Bs[rt][boff[j]];                      \
        asm volatile("s_waitcnt vmcnt(0)" ::: "memory");                    \
        asm volatile("s_barrier" ::: "memory");                             \
        MFMA_HALF(2)                                                        \
        asm volatile("s_barrier" ::: "memory");                             \
    }

    // final iter: compute only (all DMA retired; reads are wave-private)
#define ITER_FINAL(rt) {                                                    \
        bf16x8 af[4], bfv[4];                                               \
        _Pragma("unroll") for (int i = 0; i < 4; ++i)                       \
            af[i] = *(const bf16x8*)&As[rt][aoff[i]];                       \
        _Pragma("unroll") for (int j = 0; j < 4; ++j)                       \
            bfv[j] = *(const bf16x8*)&Bs[rt][boff[j]];                      \
        MFMA_HALF(0)                                                        \
        MFMA_HALF(2)                                                        \
    }

    // prologue: tiles 0 and 1 fully in flight; land tile 0 (tile 1 rides)
    GLOAD16(Ag,      AsB);
    GLOAD16(Bg0,     BsB);
    GLOAD16(Bg1,     BsB + 8192);
    GLOAD16(Ag  + 4, AsB + 8192);
    GLOAD16(Bg0 + 4, BsB + 16384);
    GLOAD16(Bg1 + 4, BsB + 16384 + 8192);
    asm volatile("s_waitcnt vmcnt(3)\n\ts_barrier" ::: "memory");

    // kt = 0..20 (buffer pattern repeats mod 3), each issues kt+2
    for (int t = 0; t < 7; ++t) {
        const int g = t * 3;
        ITER_ISSUE(0, 2, g + 2);
        ITER_ISSUE(1, 0, g + 3);
        ITER_ISSUE(2, 1, g + 4);
    }
    ITER_ISSUE(0, 2, 23);   // kt=21: issues last tile (23)
    ITER_DRAIN(1);          // kt=22: land tile 23
    ITER_FINAL(2);          // kt=23: compute only

    // epilogue: C[row][col] = acc + bias[col]  (verified layout)
    float bv[4];
#pragma unroll
    for (int j = 0; j < 4; ++j)
        bv[j] = bias[colBase + wc * 64 + j * 16 + lane16];
#pragma unroll
    for (int i = 0; i < 4; ++i) {
        int row0 = rowBase + wr * 64 + i * 16 + quad * 4;
#pragma unroll
        for (int r2 = 0; r2 < 4; ++r2) {
            float* cp = C + (size_t)(row0 + r2) * N_DIM + colBase + wc * 64 + lane16;
#pragma unroll
            for (int j = 0; j < 4; ++j)
                cp[j * 16] = acc[i][j][r2] + bv[j];
        }
    }
#undef MFMA_HALF
#undef ITER_ISSUE
#undef ITER_DRAIN
#undef ITER_FINAL
}

extern "C" void kernel_launch(void* const* d_in, const int* in_sizes, int n_in,
                              void* d_out, int out_size, void* d_ws, size_t ws_size,
                              hipStream_t stream) {
    const float* x    = (const float*)d_in[0];
    const float* w    = (const float*)d_in[1];
    const float* bias = (const float*)d_in[2];
    float* out = (float*)d_out;

    u16* xb = (u16*)d_ws;                                       // 9,633,792 B
    u16* wb = (u16*)((char*)d_ws + (size_t)M_ROWS * K_DIM * 2); // +4,718,592 B

    hipLaunchKernelGGL(prep_kernel, dim3(X_BLOCKS + W_BLOCKS), dim3(256),
                       0, stream, x, w, xb, wb);
    hipLaunchKernelGGL(gemm_bt, dim3(NWG), dim3(512),
                       0, stream, xb, wb, bias, out);
}